// Round 1
// 448.921 us; speedup vs baseline: 1.0673x; 1.0673x over previous
//
#include <hip/hip_runtime.h>

namespace {

constexpr int Sn = 256;   // encoder sequence length
constexpr int Tn = 12;    // decoder length

typedef float v2f __attribute__((ext_vector_type(2)));

__device__ __forceinline__ v2f pkfma(v2f a, v2f b, v2f c) {
  return __builtin_elementwise_fma(a, b, c);  // -> v_pk_fma_f32 on gfx950
}

__device__ __forceinline__ float rcp_(float x) { return __builtin_amdgcn_rcpf(x); }
// sigmoid(x) = 1/(1+e^-x); saturates cleanly: e^inf -> inf -> rcp -> 0
__device__ __forceinline__ float sigm_(float x) { return rcp_(1.0f + __expf(-x)); }
// tanh(x) = 1 - 2/(e^{2x}+1); x->+inf: 1-0=1, x->-inf: 1-2=-1 (no inf/inf NaN)
__device__ __forceinline__ float tanh_(float x) { return 1.0f - 2.0f * rcp_(__expf(2.0f * x) + 1.0f); }

// quad_perm DPP: lane i reads lane sel_i of its 4-lane quad. VALU-rate cross-lane.
template <int CTRL>
__device__ __forceinline__ float qperm(float v) {
  return __int_as_float(
      __builtin_amdgcn_mov_dpp(__float_as_int(v), CTRL, 0xF, 0xF, true));
}
constexpr int DPP_XOR1 = 0xB1;  // [1,0,3,2]
constexpr int DPP_XOR2 = 0x4E;  // [2,3,0,1]
constexpr int DPP_XOR3 = 0x1B;  // [3,2,1,0]
constexpr int DPP_BC0 = 0x00;   // [0,0,0,0]

// g01=(i,f), g23=(g,o) pre-activation; updates c, returns new h.
__device__ __forceinline__ float unit_update(v2f g01, v2f g23, float& c) {
  float iv = sigm_(g01.x);
  float fv = sigm_(g01.y);
  float gv = tanh_(g23.x);
  float ov = sigm_(g23.y);
  c = fmaf(fv, c, iv * gv);
  return ov * tanh_(c);
}

__device__ __forceinline__ void quad_gather(float h, float* hg) {
  hg[0] = h;
  hg[1] = qperm<DPP_XOR1>(h);
  hg[2] = qperm<DPP_XOR2>(h);
  hg[3] = qperm<DPP_XOR3>(h);
}

__global__ __launch_bounds__(64) void seq2seq_kernel(
    const float* __restrict__ src, const float* __restrict__ trg,
    const float* __restrict__ eWih0, const float* __restrict__ eWhh0,
    const float* __restrict__ ebih0, const float* __restrict__ ebhh0,
    const float* __restrict__ eWih1, const float* __restrict__ eWhh1,
    const float* __restrict__ ebih1, const float* __restrict__ ebhh1,
    const float* __restrict__ dWih0, const float* __restrict__ dWhh0,
    const float* __restrict__ dbih0, const float* __restrict__ dbhh0,
    const float* __restrict__ dWih1, const float* __restrict__ dWhh1,
    const float* __restrict__ dbih1, const float* __restrict__ dbhh1,
    const float* __restrict__ fcW, const float* __restrict__ fcb,
    float* __restrict__ out) {
  const int gid = blockIdx.x * 64 + threadIdx.x;
  const int e = gid >> 2;  // batch element
  const int u = gid & 3;   // hidden unit owned by this lane

  // Gate rows for this lane: i=u, f=4+u, g=8+u, o=12+u.
  // Packed pairs: 01=(i,f), 23=(g,o). h-indices permuted by u^k to match the
  // quad_gather register order.
  const int ri = u, rf = 4 + u, rg = 8 + u, ro = 12 + u;

  v2f w0x01[8], w0x23[8], w0h01[4], w0h23[4];
  v2f w1i01[4], w1i23[4], w1h01[4], w1h23[4];
#pragma unroll
  for (int j = 0; j < 8; ++j) {
    w0x01[j] = v2f{eWih0[ri * 8 + j], eWih0[rf * 8 + j]};
    w0x23[j] = v2f{eWih0[rg * 8 + j], eWih0[ro * 8 + j]};
  }
#pragma unroll
  for (int k = 0; k < 4; ++k) {
    const int kc = u ^ k;
    w0h01[k] = v2f{eWhh0[ri * 4 + kc], eWhh0[rf * 4 + kc]};
    w0h23[k] = v2f{eWhh0[rg * 4 + kc], eWhh0[ro * 4 + kc]};
    w1i01[k] = v2f{eWih1[ri * 4 + kc], eWih1[rf * 4 + kc]};
    w1i23[k] = v2f{eWih1[rg * 4 + kc], eWih1[ro * 4 + kc]};
    w1h01[k] = v2f{eWhh1[ri * 4 + kc], eWhh1[rf * 4 + kc]};
    w1h23[k] = v2f{eWhh1[rg * 4 + kc], eWhh1[ro * 4 + kc]};
  }
  const v2f b0_01 = v2f{ebih0[ri] + ebhh0[ri], ebih0[rf] + ebhh0[rf]};
  const v2f b0_23 = v2f{ebih0[rg] + ebhh0[rg], ebih0[ro] + ebhh0[ro]};
  const v2f b1_01 = v2f{ebih1[ri] + ebhh1[ri], ebih1[rf] + ebhh1[rf]};
  const v2f b1_23 = v2f{ebih1[rg] + ebhh1[rg], ebih1[ro] + ebhh1[ro]};

  const float4* sp = (const float4*)(src + (size_t)e * (Sn * 8));

  float h0g[4] = {0, 0, 0, 0};  // h0g[k] = h0[u^k]
  float h1g[4] = {0, 0, 0, 0};
  float c0 = 0.0f, c1 = 0.0f;

  // One full LSTM step (both layers) given this step's 8 inputs.
  auto enc_step = [&](float4 xa, float4 xb) {
    float x[8] = {xa.x, xa.y, xa.z, xa.w, xb.x, xb.y, xb.z, xb.w};
    v2f a01 = b0_01, a23 = b0_23;
#pragma unroll
    for (int j = 0; j < 8; ++j) {
      v2f xx = v2f{x[j], x[j]};
      a01 = pkfma(xx, w0x01[j], a01);
      a23 = pkfma(xx, w0x23[j], a23);
    }
#pragma unroll
    for (int k = 0; k < 4; ++k) {
      v2f hh = v2f{h0g[k], h0g[k]};
      a01 = pkfma(hh, w0h01[k], a01);
      a23 = pkfma(hh, w0h23[k], a23);
    }
    float h0 = unit_update(a01, a23, c0);
    quad_gather(h0, h0g);

    a01 = b1_01;
    a23 = b1_23;
#pragma unroll
    for (int k = 0; k < 4; ++k) {
      v2f hh0 = v2f{h0g[k], h0g[k]};
      v2f hh1 = v2f{h1g[k], h1g[k]};
      a01 = pkfma(hh0, w1i01[k], a01);
      a23 = pkfma(hh0, w1i23[k], a23);
      a01 = pkfma(hh1, w1h01[k], a01);
      a23 = pkfma(hh1, w1h23[k], a23);
    }
    float h1 = unit_update(a01, a23, c1);
    quad_gather(h1, h1g);
  };

  // ---------------- encoder: 256 steps ----------------
  // Double-buffered register FIFO, 8 steps (16 float4) per buffer.
  // Loads for a buffer are issued a full 8-step compute block (~2000+ cycles)
  // before first use, covering HBM latency (~900-1800 cy under load). The old
  // 1-step prefetch left ~700 cy/step where both resident waves stalled
  // (VALUBusy 62%, HBM 8.7% -> latency-bound, not BW/issue-bound).
  float4 A[16], B[16];
#pragma unroll
  for (int j = 0; j < 16; ++j) A[j] = sp[j];        // steps 0..7
#pragma unroll
  for (int j = 0; j < 16; ++j) B[j] = sp[16 + j];   // steps 8..15

  for (int i = 0; i < 16; ++i) {  // 16 outer iters x 16 steps = 256
#pragma unroll
    for (int s = 0; s < 8; ++s) enc_step(A[2 * s], A[2 * s + 1]);
    if (i < 15) {  // refill A with steps 16(i+1)..16(i+1)+7
#pragma unroll
      for (int j = 0; j < 16; ++j) A[j] = sp[32 * (i + 1) + j];
    }
#pragma unroll
    for (int s = 0; s < 8; ++s) enc_step(B[2 * s], B[2 * s + 1]);
    if (i < 15) {  // refill B with steps 16(i+1)+8..16(i+1)+15
#pragma unroll
      for (int j = 0; j < 16; ++j) B[j] = sp[32 * (i + 1) + 16 + j];
    }
  }

  // ---- decoder weights (loaded after encoder; encoder weights now dead) ----
  v2f dw0i01 = v2f{dWih0[ri], dWih0[rf]};
  v2f dw0i23 = v2f{dWih0[rg], dWih0[ro]};
  v2f dw0h01[4], dw0h23[4], dw1i01[4], dw1i23[4], dw1h01[4], dw1h23[4];
#pragma unroll
  for (int k = 0; k < 4; ++k) {
    const int kc = u ^ k;
    dw0h01[k] = v2f{dWhh0[ri * 4 + kc], dWhh0[rf * 4 + kc]};
    dw0h23[k] = v2f{dWhh0[rg * 4 + kc], dWhh0[ro * 4 + kc]};
    dw1i01[k] = v2f{dWih1[ri * 4 + kc], dWih1[rf * 4 + kc]};
    dw1i23[k] = v2f{dWih1[rg * 4 + kc], dWih1[ro * 4 + kc]};
    dw1h01[k] = v2f{dWhh1[ri * 4 + kc], dWhh1[rf * 4 + kc]};
    dw1h23[k] = v2f{dWhh1[rg * 4 + kc], dWhh1[ro * 4 + kc]};
  }
  const v2f db0_01 = v2f{dbih0[ri] + dbhh0[ri], dbih0[rf] + dbhh0[rf]};
  const v2f db0_23 = v2f{dbih0[rg] + dbhh0[rg], dbih0[ro] + dbhh0[ro]};
  const v2f db1_01 = v2f{dbih1[ri] + dbhh1[ri], dbih1[rf] + dbhh1[rf]};
  const v2f db1_23 = v2f{dbih1[rg] + dbhh1[rg], dbih1[ro] + dbhh1[ro]};
  float fcw[4];
#pragma unroll
  for (int k = 0; k < 4; ++k) fcw[k] = fcW[u ^ k];
  const float fcbv = fcb[0];

  // ---------------- decoder: 11 steps ----------------
  float xv = trg[(size_t)e * Tn];  // trg[e, 0, 0]
  if (u == 0) out[(size_t)e * Tn] = xv;

  for (int t = 1; t < Tn; ++t) {
    v2f xx = v2f{xv, xv};
    v2f a01 = pkfma(xx, dw0i01, db0_01);
    v2f a23 = pkfma(xx, dw0i23, db0_23);
#pragma unroll
    for (int k = 0; k < 4; ++k) {
      v2f hh = v2f{h0g[k], h0g[k]};
      a01 = pkfma(hh, dw0h01[k], a01);
      a23 = pkfma(hh, dw0h23[k], a23);
    }
    float h0 = unit_update(a01, a23, c0);
    quad_gather(h0, h0g);

    a01 = db1_01;
    a23 = db1_23;
#pragma unroll
    for (int k = 0; k < 4; ++k) {
      v2f hh0 = v2f{h0g[k], h0g[k]};
      v2f hh1 = v2f{h1g[k], h1g[k]};
      a01 = pkfma(hh0, dw1i01[k], a01);
      a23 = pkfma(hh0, dw1i23[k], a23);
      a01 = pkfma(hh1, dw1h01[k], a01);
      a23 = pkfma(hh1, dw1h23[k], a23);
    }
    float h1 = unit_update(a01, a23, c1);
    quad_gather(h1, h1g);

    float pred = fcbv;
#pragma unroll
    for (int k = 0; k < 4; ++k) pred = fmaf(h1g[k], fcw[k], pred);
    // broadcast lane0's pred so all quad lanes stay bit-identical
    pred = qperm<DPP_BC0>(pred);
    if (u == 0) out[(size_t)e * Tn + t] = pred;
    xv = pred;
  }
}

}  // namespace

extern "C" void kernel_launch(void* const* d_in, const int* in_sizes, int n_in,
                              void* d_out, int out_size, void* d_ws, size_t ws_size,
                              hipStream_t stream) {
  const float* src = (const float*)d_in[0];
  const float* trg = (const float*)d_in[1];
  const float* eWih0 = (const float*)d_in[2];
  const float* eWhh0 = (const float*)d_in[3];
  const float* ebih0 = (const float*)d_in[4];
  const float* ebhh0 = (const float*)d_in[5];
  const float* eWih1 = (const float*)d_in[6];
  const float* eWhh1 = (const float*)d_in[7];
  const float* ebih1 = (const float*)d_in[8];
  const float* ebhh1 = (const float*)d_in[9];
  const float* dWih0 = (const float*)d_in[10];
  const float* dWhh0 = (const float*)d_in[11];
  const float* dbih0 = (const float*)d_in[12];
  const float* dbhh0 = (const float*)d_in[13];
  const float* dWih1 = (const float*)d_in[14];
  const float* dWhh1 = (const float*)d_in[15];
  const float* dbih1 = (const float*)d_in[16];
  const float* dbhh1 = (const float*)d_in[17];
  const float* fcW = (const float*)d_in[18];
  const float* fcb = (const float*)d_in[19];
  float* out = (float*)d_out;

  const int B = 32768;
  const int lanes = B * 4;          // 4 lanes per batch element
  const int block = 64;
  const int grid = lanes / block;   // 2048 blocks -> 8 waves/CU, 2/SIMD
  seq2seq_kernel<<<grid, block, 0, stream>>>(
      src, trg, eWih0, eWhh0, ebih0, ebhh0, eWih1, eWhh1, ebih1, ebhh1,
      dWih0, dWhh0, dbih0, dbhh0, dWih1, dWhh1, dbih1, dbhh1, fcW, fcb, out);
}